// Round 5
// baseline (280.507 us; speedup 1.0000x reference)
//
#include <hip/hip_runtime.h>
#include <hip/hip_bf16.h>
#include <stdint.h>

#define MDIM 4096
#define NDIM 4096
#define KDIM 4096
#define NT   (KDIM / 64)   // 64 K-tiles of depth 64

typedef __attribute__((ext_vector_type(8))) short bf16x8;      // MFMA A/B frag (4 VGPRs)
typedef __attribute__((ext_vector_type(4))) float floatx4;     // MFMA C/D frag
typedef __attribute__((ext_vector_type(8))) unsigned short ushort8_t;
typedef __attribute__((ext_vector_type(4))) unsigned short ushort4_t;

// fp32 -> bf16 round-to-nearest-even
__device__ __forceinline__ unsigned short f2bf(float f) {
  union { float f; uint32_t u; } v; v.f = f;
  uint32_t u = v.u;
  u += 0x7FFFu + ((u >> 16) & 1u);
  return (unsigned short)(u >> 16);
}

// async global->LDS, 16B/lane. LDS dest = wave-uniform base + lane*16 (m104/m108).
__device__ __forceinline__ void async_copy16(unsigned short* lds, const unsigned short* g) {
  __builtin_amdgcn_global_load_lds((const __attribute__((address_space(1))) void*)g,
                                   (__attribute__((address_space(3))) void*)lds,
                                   16, 0, 0);
}

// ---------------- fp32 -> bf16 conversion into workspace (unchanged from R3) ----------------
__global__ __launch_bounds__(256) void convert_bf16(const float* __restrict__ x,
                                                    const float* __restrict__ w,
                                                    unsigned short* __restrict__ xb,
                                                    unsigned short* __restrict__ wb) {
  const int half = gridDim.x >> 1;
  const float* src;
  unsigned short* dst;
  int b = blockIdx.x;
  if (b < half) { src = x; dst = xb; } else { src = w; dst = wb; b -= half; }
  const int64_t total  = (int64_t)MDIM * KDIM;
  const int64_t stride = (int64_t)half * 256 * 4;
  for (int64_t off = ((int64_t)b * 256 + threadIdx.x) * 4; off < total; off += stride) {
    float4 v = *(const float4*)(src + off);
    ushort4_t a = {f2bf(v.x), f2bf(v.y), f2bf(v.z), f2bf(v.w)};
    *(ushort4_t*)(dst + off) = a;
  }
}

// ---------------- 256x256 4-phase bf16 MFMA GEMM, deep staging pipeline ----------------
// v5: staging window shifted ONE PHASE EARLIER than v4. Region-liveness proof:
// buffer X's last ds_reads for tile t-1 (A1 @P1(t-1)) drain at P2(t-1)'s
// lgkmcnt before its closing barrier, so staging tile t+1 -> X may start at
// P3(t-1). Schedule: A0'(t+1)@P3(t-1), B0'@P0(t), B1'@P1(t), A1'@P2(t).
//
// Per-wave vmcnt FIFO (2 instr/unit), waits BEFORE the closing barrier:
//   end P0(t): out=[A1(t),A0',B0']=6 -> vmcnt(4) confirms A1(t)   (read P1(t))
//   end P1(t): no wait
//   end P2(t): out=[A0',B0',B1',A1']=8 -> vmcnt(4) confirms A0',B0' (read P3(t))
//   end P3(t): out=[B1',A1',A0'']=6 -> vmcnt(4) confirms B1'      (read P0(t+1))
// In-flight spans 2.8-3.8 phases (~2200-3000 cyc) >> worst-case HBM ~900 cyc.
// Write-hazard: every stage target is >=3 barriers past the lgkm-drain of its
// last reads (A0/B0 regions read P3(t-2), drained P0(t-1); B1 read P0(t-1),
// drained P1(t-1); A1 read P1(t-1), drained P2(t-1)). Cross-wave publication:
// each wave's vmcnt confirms its own slice, then the barrier fans it out.
__global__ __launch_bounds__(512, 2) void gemm_bf16(const unsigned short* __restrict__ A,
                                                    const unsigned short* __restrict__ B,
                                                    const float* __restrict__ bias,
                                                    float* __restrict__ C) {
  __shared__ __align__(16) unsigned short S[2][32768];  // 128 KiB
  const int tid = threadIdx.x;
  // bijective XCD rectangle swizzle: XCD c owns a 4(bm) x 8(bn) rectangle.
  const int id = blockIdx.x;
  const int xcd = id & 7, sblk = id >> 3;
  const int bm = (xcd >> 1) * 4 + (sblk >> 3);
  const int bn = (xcd & 1) * 8 + (sblk & 7);
  const int lane = tid & 63;
  const int wave = tid >> 6;                 // 8 waves
  const int quad = lane >> 4, r16 = lane & 15;
  const int wm = wave >> 2, wn = wave & 3;   // 2x4 wave grid; wave tile 128x64

  // staging constants (512 threads, 16B each; one issue = 8KB = 64 rows)
  const int rowa = tid >> 3;                 // 0..63
  const int slot = tid & 7;
  const int ch = slot ^ (rowa & 7);          // swizzled 16B chunk fetched
  const unsigned short* gA0 = A + (int64_t)(bm * 256 + rowa) * KDIM + ch * 8;
  const int growb = (rowa >> 5) * 64 + (rowa & 31);
  const unsigned short* gB0 = B + (int64_t)(bn * 256 + growb) * KDIM + ch * 8;

  // ds_read constants (shorts)
  const int offA = wm * 4096 + r16 * 64;
  const int offB = 16384 + wn * 2048 + r16 * 64;
  const int sw0 = (quad ^ (r16 & 7)) * 8;    // k-step h=0 chunk offset
  const int sw1 = sw0 ^ 32;                  // k-step h=1 (chunk ^ 4)

  floatx4 acc[8][4] = {};
  bf16x8 avA[4][2], avB[4][2];   // A0 / A1 fragment sets
  bf16x8 bvB[2][2];              // B1 fragments
  bf16x8 bvE[2][2], bvO[2][2];   // B0 fragments, even / odd tile parity

#define STAGE_A(BUF, MH, TT) do { \
    unsigned short* d_ = &S[BUF][(MH) * 8192 + tid * 8]; \
    const unsigned short* s_ = gA0 + (int64_t)((MH) * 64) * KDIM + (TT) * 64; \
    async_copy16(d_, s_); \
    async_copy16(d_ + 4096, s_ + (int64_t)128 * KDIM); \
  } while (0)

#define STAGE_B(BUF, NH, TT) do { \
    unsigned short* d_ = &S[BUF][16384 + (NH) * 8192 + tid * 8]; \
    const unsigned short* s_ = gB0 + (int64_t)((NH) * 32) * KDIM + (TT) * 64; \
    async_copy16(d_, s_); \
    async_copy16(d_ + 4096, s_ + (int64_t)128 * KDIM); \
  } while (0)

#define RD_A(DST, BUF, MH) do { \
    const unsigned short* Sb_ = &S[BUF][0]; \
    _Pragma("unroll") \
    for (int i = 0; i < 4; ++i) { \
      DST[i][0] = *(const bf16x8*)(Sb_ + (MH) * 8192 + offA + i * 1024 + sw0); \
      DST[i][1] = *(const bf16x8*)(Sb_ + (MH) * 8192 + offA + i * 1024 + sw1); \
    } \
  } while (0)

#define RD_B(DST, BUF, NH) do { \
    const unsigned short* Sb_ = &S[BUF][0]; \
    _Pragma("unroll") \
    for (int j = 0; j < 2; ++j) { \
      DST[j][0] = *(const bf16x8*)(Sb_ + (NH) * 8192 + offB + j * 1024 + sw0); \
      DST[j][1] = *(const bf16x8*)(Sb_ + (NH) * 8192 + offB + j * 1024 + sw1); \
    } \
  } while (0)

#define VM4 asm volatile("s_waitcnt vmcnt(4)" ::: "memory")
#define VMNONE (void)0

  // AV/BV: operand sets for THIS phase's MFMA (loaded in an earlier phase).
  // READ_STMT: ds_reads for a later phase. LGKM_LIT: count of just-issued reads.
#define PHASE(AV, BV, MOFF, NOFF, READ_STMT, STAGE_STMT, LGKM_LIT, WAIT_STMT) do { \
    READ_STMT; \
    STAGE_STMT; \
    asm volatile("s_waitcnt lgkmcnt(" LGKM_LIT ")" ::: "memory"); \
    __builtin_amdgcn_sched_barrier(0); \
    __builtin_amdgcn_s_setprio(1); \
    _Pragma("unroll") \
    for (int h = 0; h < 2; ++h) \
      _Pragma("unroll") \
      for (int i = 0; i < 4; ++i) \
        _Pragma("unroll") \
        for (int j = 0; j < 2; ++j) \
          acc[(MOFF) + i][(NOFF) + j] = __builtin_amdgcn_mfma_f32_16x16x32_bf16( \
              AV[i][h], BV[j][h], acc[(MOFF) + i][(NOFF) + j], 0, 0, 0); \
    __builtin_amdgcn_s_setprio(0); \
    WAIT_STMT; \
    __builtin_amdgcn_s_barrier(); \
    __builtin_amdgcn_sched_barrier(0); \
  } while (0)

  // prologue (FIFO): A0(0),B0(0),B1(0),A1(0),A0(1); vmcnt(4) confirms the
  // first three units, leaving [A1(0), A0(1)] in flight = steady-state shape.
  STAGE_A(0, 0, 0);
  STAGE_B(0, 0, 0);
  STAGE_B(0, 1, 0);
  STAGE_A(0, 1, 0);
  STAGE_A(1, 0, 1);
  asm volatile("s_waitcnt vmcnt(4)" ::: "memory");
  __builtin_amdgcn_s_barrier();
  RD_A(avA, 0, 0);
  RD_B(bvE, 0, 0);

  for (int it = 0; it < NT / 2; ++it) {
    const int u = it * 2;
    const int t1 = u + 1;
    const int t2 = (u + 2) & (NT - 1);   // wrapped at tail: staged/read but never used
    const int t3 = (u + 3) & (NT - 1);
    // tile u (buf0, B0 in bvE)
    PHASE(avA, bvE, 0, 0, RD_B(bvB, 0, 1),                       STAGE_B(1, 0, t1), "4",  VM4);
    PHASE(avA, bvB, 0, 2, RD_A(avB, 0, 1),                       STAGE_B(1, 1, t1), "8",  VMNONE);
    PHASE(avB, bvB, 4, 2, (void)0,                               STAGE_A(1, 1, t1), "0",  VM4);
    PHASE(avB, bvE, 4, 0, { RD_A(avA, 1, 0); RD_B(bvO, 1, 0); }, STAGE_A(0, 0, t2), "12", VM4);
    // tile t1 (buf1, B0 in bvO)
    PHASE(avA, bvO, 0, 0, RD_B(bvB, 1, 1),                       STAGE_B(0, 0, t2), "4",  VM4);
    PHASE(avA, bvB, 0, 2, RD_A(avB, 1, 1),                       STAGE_B(0, 1, t2), "8",  VMNONE);
    PHASE(avB, bvB, 4, 2, (void)0,                               STAGE_A(0, 1, t2), "0",  VM4);
    PHASE(avB, bvO, 4, 0, { RD_A(avA, 0, 0); RD_B(bvE, 0, 0); }, STAGE_A(1, 0, t3), "12", VM4);
  }
  asm volatile("s_waitcnt vmcnt(0)" ::: "memory");

#undef PHASE
#undef VM4
#undef VMNONE
#undef RD_A
#undef RD_B
#undef STAGE_A
#undef STAGE_B

  // epilogue: C/D layout col = lane&15, row = quad*4 + r (m89-verified)
  const int col0 = bn * 256 + wn * 64 + r16;
  const int row0 = bm * 256 + wm * 128 + quad * 4;
#pragma unroll
  for (int nj = 0; nj < 4; ++nj) {
    const float bvv = bias[col0 + nj * 16];
#pragma unroll
    for (int mi = 0; mi < 8; ++mi) {
      float* cp = C + (int64_t)(row0 + mi * 16) * NDIM + col0 + nj * 16;
#pragma unroll
      for (int r = 0; r < 4; ++r)
        cp[(int64_t)r * NDIM] = acc[mi][nj][r] + bvv;
    }
  }
}

// ---------------- fallback: fp32 inputs, convert in staging (no workspace) ----------------
#define BM 128
#define BN 128
#define FBK 32
__global__ __launch_bounds__(256) void gemm_f32in(const float* __restrict__ A,
                                                  const float* __restrict__ W,
                                                  const float* __restrict__ bias,
                                                  float* __restrict__ C) {
  __shared__ __align__(16) unsigned short As[BM * FBK];
  __shared__ __align__(16) unsigned short Bs[BN * FBK];
  const int tid = threadIdx.x;
  const int bm = blockIdx.y, bn = blockIdx.x;
  const int lane = tid & 63, wave = tid >> 6;
  const int quad = lane >> 4, r16 = lane & 15;
  const int wm = (wave >> 1) * 64, wn = (wave & 1) * 64;

  const int srow = tid >> 1;
  const int scol = (tid & 1) * 16;
  const float* ag = A + (int64_t)(bm * BM + srow) * KDIM + scol;
  const float* bg = W + (int64_t)(bn * BN + srow) * KDIM + scol;
  unsigned short* al = As + srow * FBK + scol;
  unsigned short* bl = Bs + srow * FBK + scol;

  floatx4 acc[4][4] = {};
  for (int k0 = 0; k0 < KDIM; k0 += FBK) {
    float4 a0 = *(const float4*)(ag + k0);
    float4 a1 = *(const float4*)(ag + k0 + 4);
    float4 a2 = *(const float4*)(ag + k0 + 8);
    float4 a3 = *(const float4*)(ag + k0 + 12);
    float4 b0 = *(const float4*)(bg + k0);
    float4 b1 = *(const float4*)(bg + k0 + 4);
    float4 b2 = *(const float4*)(bg + k0 + 8);
    float4 b3 = *(const float4*)(bg + k0 + 12);
    ushort8_t pa0 = {f2bf(a0.x), f2bf(a0.y), f2bf(a0.z), f2bf(a0.w),
                     f2bf(a1.x), f2bf(a1.y), f2bf(a1.z), f2bf(a1.w)};
    ushort8_t pa1 = {f2bf(a2.x), f2bf(a2.y), f2bf(a2.z), f2bf(a2.w),
                     f2bf(a3.x), f2bf(a3.y), f2bf(a3.z), f2bf(a3.w)};
    ushort8_t pb0 = {f2bf(b0.x), f2bf(b0.y), f2bf(b0.z), f2bf(b0.w),
                     f2bf(b1.x), f2bf(b1.y), f2bf(b1.z), f2bf(b1.w)};
    ushort8_t pb1 = {f2bf(b2.x), f2bf(b2.y), f2bf(b2.z), f2bf(b2.w),
                     f2bf(b3.x), f2bf(b3.y), f2bf(b3.z), f2bf(b3.w)};
    *(ushort8_t*)al = pa0;
    *(ushort8_t*)(al + 8) = pa1;
    *(ushort8_t*)bl = pb0;
    *(ushort8_t*)(bl + 8) = pb1;
    __syncthreads();

    bf16x8 a[4], b[4];
#pragma unroll
    for (int i = 0; i < 4; ++i)
      a[i] = *(const bf16x8*)(As + (wm + i * 16 + r16) * FBK + quad * 8);
#pragma unroll
    for (int i = 0; i < 4; ++i)
      b[i] = *(const bf16x8*)(Bs + (wn + i * 16 + r16) * FBK + quad * 8);
#pragma unroll
    for (int i = 0; i < 4; ++i)
#pragma unroll
      for (int j = 0; j < 4; ++j)
        acc[i][j] = __builtin_amdgcn_mfma_f32_16x16x32_bf16(a[i], b[j], acc[i][j], 0, 0, 0);
    __syncthreads();
  }

  const int col0 = bn * BN + wn + r16;
  const int row0 = bm * BM + wm + quad * 4;
#pragma unroll
  for (int j = 0; j < 4; ++j) {
    const float bv = bias[col0 + j * 16];
#pragma unroll
    for (int i = 0; i < 4; ++i) {
      float* cp = C + (int64_t)(row0 + i * 16) * NDIM + col0 + j * 16;
#pragma unroll
      for (int r = 0; r < 4; ++r)
        cp[(int64_t)r * NDIM] = acc[i][j][r] + bv;
    }
  }
}

extern "C" void kernel_launch(void* const* d_in, const int* in_sizes, int n_in,
                              void* d_out, int out_size, void* d_ws, size_t ws_size,
                              hipStream_t stream) {
  const float* x    = (const float*)d_in[0];   // [4096, 4096]
  const float* w    = (const float*)d_in[1];   // [4096, 4096]
  const float* bias = (const float*)d_in[2];   // [4096]
  float* out = (float*)d_out;

  const size_t need = (size_t)2 * MDIM * KDIM * sizeof(unsigned short);  // 64 MB
  if (ws_size >= need) {
    unsigned short* xb = (unsigned short*)d_ws;
    unsigned short* wb = xb + (size_t)MDIM * KDIM;
    convert_bf16<<<4096, 256, 0, stream>>>(x, w, xb, wb);
    gemm_bf16<<<256, 512, 0, stream>>>(xb, wb, bias, out);  // 1-D grid, XCD-swizzled in-kernel
  } else {
    dim3 grid(NDIM / BN, MDIM / BM);
    gemm_f32in<<<grid, 256, 0, stream>>>(x, w, bias, out);
  }
}